// Round 4
// baseline (613.226 us; speedup 1.0000x reference)
//
#include <hip/hip_runtime.h>

typedef unsigned short u16;
typedef unsigned int   u32;
typedef __attribute__((ext_vector_type(4))) float  f32x4;
typedef __attribute__((ext_vector_type(8))) short  s16x8;
typedef __attribute__((ext_vector_type(8))) __bf16 bf16x8;
typedef __attribute__((ext_vector_type(2))) u32    u32x2;

#define DEV __device__ __forceinline__
#define SCALE_Q 0.1889822365046136f   // 28^-0.5

DEV float bf2f(u16 u){ u32 x = ((u32)u)<<16; float f; __builtin_memcpy(&f,&x,4); return f; }
DEV u16   f2bf(float f){ u32 x; __builtin_memcpy(&x,&f,4); return (u16)((x + 0x7fffu + ((x>>16)&1u))>>16); }

DEV s16x8 cvt8(const float* __restrict__ src){
  f32x4 f0 = *(const f32x4*)src, f1 = *(const f32x4*)(src+4);
  bf16x8 b;
  b[0]=(__bf16)f0[0]; b[1]=(__bf16)f0[1]; b[2]=(__bf16)f0[2]; b[3]=(__bf16)f0[3];
  b[4]=(__bf16)f1[0]; b[5]=(__bf16)f1[1]; b[6]=(__bf16)f1[2]; b[7]=(__bf16)f1[3];
  return __builtin_bit_cast(s16x8, b);
}

// async global->LDS, 16B per lane. LDS dest = wave-uniform base + lane*16.
DEV void gll16(const u16* g, u16* l){
  __builtin_amdgcn_global_load_lds(
      (const __attribute__((address_space(1))) u32*)(const void*)g,
      (__attribute__((address_space(3))) u32*)(void*)l,
      16, 0, 0);
}

DEV void ld28(const u16* __restrict__ p, float* dst, float scale){
#pragma unroll
  for (int j=0;j<7;j++){
    u32x2 w = *(const u32x2*)(p + j*4);
    dst[j*4+0] = bf2f((u16)(w[0]&0xffffu))*scale;
    dst[j*4+1] = bf2f((u16)(w[0]>>16))*scale;
    dst[j*4+2] = bf2f((u16)(w[1]&0xffffu))*scale;
    dst[j*4+3] = bf2f((u16)(w[1]>>16))*scale;
  }
}

// ---------------------------------------------------------------------------
// pack_k: f32 weights -> bf16 packed.
//  WqkvT [672][224], WoutT [448][224], convW [4][224][2016] ([conv][co][tap*224+ci], kd=1)
// ---------------------------------------------------------------------------
__global__ void pack_k(const float* __restrict__ Wq, const float* __restrict__ Wkv,
                       const float* __restrict__ Wout,
                       const float* __restrict__ wr, const float* __restrict__ w1,
                       const float* __restrict__ w2, const float* __restrict__ w3,
                       u16* __restrict__ WqkvT, u16* __restrict__ WoutT,
                       u16* __restrict__ convW)
{
  int idx = blockIdx.x*256 + threadIdx.x;
  if (idx < 150528) {
    int nn = idx/224, k = idx - nn*224;
    float v;
    if (nn < 224)      v = Wq [k*224 + nn];
    else if (nn < 448) v = Wkv[k*448 + (nn-224)];
    else               v = Wkv[k*448 + (nn-448) + 224];
    WqkvT[idx] = f2bf(v);
  } else if (idx < 250880) {
    int j = idx - 150528;
    int nn = j/224, k = j - nn*224;
    WoutT[j] = f2bf(Wout[k*448 + nn]);
  } else {
    int j = idx - 250880;
    int cv = j/451584, rem = j - cv*451584;
    int co = rem/2016, kk = rem - co*2016;
    int tap = kk/224, ci = kk - tap*224;
    const float* w = (cv==0)?wr:(cv==1)?w1:(cv==2)?w2:w3;
    convW[j] = f2bf(w[(co*224 + ci)*27 + 9 + tap]);
  }
}

// ---------------------------------------------------------------------------
// prep_k: x(f32,[65536][448]) -> x1bf (bf16 flat [65536][224])
//         and xpad (bf16 padded [64][34][34][224], zero borders);
//         also zero-borders oApad/oBpad.  73984 pixels * 28 chunks of 8ch.
// ---------------------------------------------------------------------------
__global__ void prep_k(const float* __restrict__ x, u16* __restrict__ x1bf,
                       u16* __restrict__ xpad, u16* __restrict__ oApad,
                       u16* __restrict__ oBpad)
{
  int idx = blockIdx.x*256 + threadIdx.x;   // 8092*256 = 2,071,552 = 73984*28
  int pp = idx/28, c8 = idx - pp*28;
  int b = pp/1156, rem = pp - b*1156, y = rem/34, xx = rem - y*34;
  int c0 = c8*8;
  if (y>=1 && y<=32 && xx>=1 && xx<=32){
    int p = (b*32 + y-1)*32 + (xx-1);
    *(s16x8*)(x1bf + p*224 + c0) = cvt8(x + p*448 + c0);
    *(s16x8*)(xpad + pp*224 + c0) = cvt8(x + p*448 + 224 + c0);
  } else {
    const s16x8 z = {0,0,0,0,0,0,0,0};
    *(s16x8*)(xpad  + pp*224 + c0) = z;
    *(s16x8*)(oApad + pp*224 + c0) = z;
    *(s16x8*)(oBpad + pp*224 + c0) = z;
  }
}

// ---------------------------------------------------------------------------
// GEMM: C[65536 x 224-per-nb] = A[65536 x K] * Bt^T (Bt [N][K] bf16).
// BM=256, BN=224, BK=32, 512 thr (8 waves 4Mx2N), wave tile 64x112 (4x7 frags).
// global_load_lds staging (A: 1024 16B-chunks, B: 896), double-buffered LDS,
// 2-phase pipeline: prologue stage; per iter {stage next, ds_read cur, MFMA, bar}.
// ---------------------------------------------------------------------------
enum { M_FUSED=0, M_C2=1, M_C3=2, M_QKV=3, M_OUT=4 };

template<int MODE>
__global__ __launch_bounds__(512,1) void gemm_k(
    const u16* __restrict__ A, const u16* __restrict__ Bt,
    const float* __restrict__ bias0, const float* __restrict__ bias1,
    u16* __restrict__ outA, u16* __restrict__ outB, float* __restrict__ outF)
{
  constexpr bool CONV = (MODE==M_FUSED || MODE==M_C2 || MODE==M_C3);
  constexpr int KTOT = CONV ? 2016 : 224;
  constexpr int KS   = KTOT/32;

  __shared__ __align__(16) u16 Als[2][256*32];   // 32 KB
  __shared__ __align__(16) u16 Bls[2][224*32];   // 28 KB

  const int t  = threadIdx.x;
  const int bm = blockIdx.x, nb = blockIdx.y;
  const int lane = t&63, lr = lane&15, lg = lane>>4;
  const int w = t>>6, wm = w>>1, wn = w&1;
  const int aq8 = (t&3)*8;

  // ---- staging source addresses ----
  const int r0 = t>>2;
  const int p0 = bm*256 + r0, p1 = p0 + 128;
  int PP0=0, PP1=0;
  if constexpr (CONV){
    PP0 = ((p0>>10)*34 + ((p0>>5)&31) + 1)*34 + (p0&31) + 1;
    PP1 = ((p1>>10)*34 + ((p1>>5)&31) + 1)*34 + (p1&31) + 1;
  }
  const int Bb0 = (nb*224 +       r0)*KTOT + aq8;
  const int Bb1 = (nb*224 + 128 + r0)*KTOT + aq8;

  // LDS dest wave bases (chunk t -> byte t*16; chunk 512+t -> +8192B)
  u16* aL[2] = { &Als[0][0] + w*512, &Als[1][0] + w*512 };
  u16* bL[2] = { &Bls[0][0] + w*512, &Bls[1][0] + w*512 };

  auto STAGE = [&](int buf, int ks){
    if constexpr (CONV){
      const int tap = ks/7, kc = ks - tap*7;
      const int ty = tap/3, tx = tap - ty*3;
      const int toff = (ty-1)*34 + (tx-1);
      const int ke = kc*32 + aq8;
      gll16(A + (PP0+toff)*224 + ke, aL[buf]);
      gll16(A + (PP1+toff)*224 + ke, aL[buf] + 4096);
    } else {
      gll16(A + p0*224 + ks*32 + aq8, aL[buf]);
      gll16(A + p1*224 + ks*32 + aq8, aL[buf] + 4096);
    }
    gll16(Bt + Bb0 + ks*32, bL[buf]);
    if (w < 6) gll16(Bt + Bb1 + ks*32, bL[buf] + 4096);
  };

  f32x4 acc[4][7];
  { f32x4 zf = {0.f,0.f,0.f,0.f};
#pragma unroll
    for (int i=0;i<4;i++)
#pragma unroll
      for (int j=0;j<7;j++) acc[i][j] = zf; }

  STAGE(0, 0);
  __syncthreads();   // drains vmcnt(0): buf0 ready

  for (int ks=0; ks<KS; ++ks){
    const int cur = ks&1;
    if (ks+1 < KS) STAGE(cur^1, ks+1);   // prefetch overlaps this iter's compute

    const u16* Ac = &Als[cur][0];
    const u16* Bc = &Bls[cur][0];
    bf16x8 af[4], bfv[7];
#pragma unroll
    for (int mi=0; mi<4; ++mi)
      af[mi] = *(const bf16x8*)(Ac + (wm*64 + mi*16 + lr)*32 + lg*8);
#pragma unroll
    for (int ni=0; ni<7; ++ni)
      bfv[ni] = *(const bf16x8*)(Bc + (wn*112 + ni*16 + lr)*32 + lg*8);

#pragma unroll
    for (int ni=0; ni<7; ++ni)
#pragma unroll
      for (int mi=0; mi<4; ++mi)
        acc[mi][ni] = __builtin_amdgcn_mfma_f32_16x16x32_bf16(af[mi], bfv[ni], acc[mi][ni], 0,0,0);

    __syncthreads();   // drains vmcnt(0) (prefetch landed) + protects cur for overwrite
  }

  // ---- epilogue ----
  const float* bs;
  if constexpr (MODE==M_FUSED) bs = (nb==0) ? bias0 : bias1;
  else bs = bias0;

#pragma unroll
  for (int mi=0; mi<4; ++mi){
    const int rbase = bm*256 + wm*64 + mi*16 + lg*4;
#pragma unroll
    for (int ni=0; ni<7; ++ni){
      const int col = wn*112 + ni*16 + lr;
#pragma unroll
      for (int r=0;r<4;r++){
        const int row = rbase + r;
        float v = acc[mi][ni][r];
        if constexpr (MODE==M_FUSED){
          v = fmaxf(v + bs[col], 0.f);
          if (nb==0){
            outF[row*672 + 448 + col] = v;         // res (f32, lives in d_out)
          } else {
            const int pp = ((row>>10)*34 + ((row>>5)&31) + 1)*34 + (row&31) + 1;
            outB[pp*224 + col] = f2bf(v);          // conv1 out (padded)
          }
        } else if constexpr (MODE==M_C2){
          v = fmaxf(v + bs[col], 0.f);
          const int pp = ((row>>10)*34 + ((row>>5)&31) + 1)*34 + (row&31) + 1;
          outB[pp*224 + col] = f2bf(v);            // conv2 out (padded)
        } else if constexpr (MODE==M_C3){
          v = fmaxf(v + bs[col], 0.f);
          const int o = row*672 + 448 + col;
          outF[o] = v + outF[o];                   // X2S = relu(conv3)+res
        } else if constexpr (MODE==M_QKV){
          outA[row*672 + nb*224 + col] = f2bf(v);  // qkv bf16 ws
        } else {                                   // M_OUT
          outF[row*672 + nb*224 + col] = v + bs[nb*224 + col];
        }
      }
    }
  }
}

// ---------------------------------------------------------------------------
// Branch-1 attention (unchanged from passing round)
// ---------------------------------------------------------------------------
__global__ __launch_bounds__(256,2) void attn1_k(const u16* __restrict__ qkv,
    const float* __restrict__ pos1, u16* __restrict__ attnout)
{
  __shared__ __align__(16) float KL[64][112];
  __shared__ __align__(16) float VL[64][112];
  const int t = threadIdx.x;
  const int b = blockIdx.x>>4, n = blockIdx.x&15;
  const int base = b*1024 + (n>>2)*256 + (n&3)*8;
  {
    const int r = t>>2, part = t&3;
    const int pr_ = base + (r>>3)*32 + (r&7);
    const u16* kp = qkv + pr_*672 + 224 + part*28;
    const u16* vp = kp + 224;
#pragma unroll
    for (int j=0;j<7;j++){
      u32x2 kk = *(const u32x2*)(kp + j*4);
      u32x2 vv = *(const u32x2*)(vp + j*4);
      const int c = part*28 + j*4;
      KL[r][c+0]=bf2f((u16)(kk[0]&0xffffu)); KL[r][c+1]=bf2f((u16)(kk[0]>>16));
      KL[r][c+2]=bf2f((u16)(kk[1]&0xffffu)); KL[r][c+3]=bf2f((u16)(kk[1]>>16));
      VL[r][c+0]=bf2f((u16)(vv[0]&0xffffu)); VL[r][c+1]=bf2f((u16)(vv[0]>>16));
      VL[r][c+2]=bf2f((u16)(vv[1]&0xffffu)); VL[r][c+3]=bf2f((u16)(vv[1]>>16));
    }
  }
  __syncthreads();

  const int h = t>>6, i = t&63;
  const int pi = base + (i>>3)*32 + (i&7);
  float q[28];
  ld28(qkv + pi*672 + h*28, q, SCALE_Q);

  float s[64];
  const float* pr = pos1 + (h*64+i)*64;
#pragma unroll
  for (int j4=0;j4<16;j4++){
    f32x4 pv = *(const f32x4*)(pr + j4*4);
    s[j4*4+0]=pv[0]; s[j4*4+1]=pv[1]; s[j4*4+2]=pv[2]; s[j4*4+3]=pv[3];
  }
  const int c0 = h*28;
#pragma unroll
  for (int j=0;j<64;j++){
    const f32x4* kr = (const f32x4*)&KL[j][c0];
    float a0=0.f,a1=0.f,a2=0.f,a3=0.f;
#pragma unroll
    for (int u=0;u<7;u++){
      f32x4 kv = kr[u];
      a0 += q[u*4+0]*kv[0]; a1 += q[u*4+1]*kv[1];
      a2 += q[u*4+2]*kv[2]; a3 += q[u*4+3]*kv[3];
    }
    s[j] += (a0+a1)+(a2+a3);
  }
  float mx = s[0];
#pragma unroll
  for (int j=1;j<64;j++) mx = fmaxf(mx, s[j]);
  float sum = 0.f;
#pragma unroll
  for (int j=0;j<64;j++){ float e = __expf(s[j]-mx); s[j]=e; sum+=e; }
  const float inv = 1.f/sum;

  float out[28];
#pragma unroll
  for (int u=0;u<28;u++) out[u]=0.f;
#pragma unroll
  for (int j=0;j<64;j++){
    const float pj = s[j];
    const f32x4* vr = (const f32x4*)&VL[j][c0];
#pragma unroll
    for (int u=0;u<7;u++){
      f32x4 vv = vr[u];
      out[u*4+0] += pj*vv[0]; out[u*4+1] += pj*vv[1];
      out[u*4+2] += pj*vv[2]; out[u*4+3] += pj*vv[3];
    }
  }
  u16* op = attnout + pi*224 + h*28;
#pragma unroll
  for (int u=0;u<7;u++){
    u32x2 wv;
    wv[0] = (u32)f2bf(out[u*4+0]*inv) | ((u32)f2bf(out[u*4+1]*inv)<<16);
    wv[1] = (u32)f2bf(out[u*4+2]*inv) | ((u32)f2bf(out[u*4+3]*inv)<<16);
    *(u32x2*)(op + u*4) = wv;
  }
}

// ---------------------------------------------------------------------------
// Branch-2 attention (unchanged from passing round)
// ---------------------------------------------------------------------------
__global__ __launch_bounds__(256,1) void attn2_k(const u16* __restrict__ qkv,
    const float* __restrict__ pos2, u16* __restrict__ attnout)
{
  const int t = threadIdx.x;
  const int b = blockIdx.x>>4, mg = blockIdx.x&15;
  const int m = mg*4 + (t>>6);
  const int lane = t&63, h = lane>>4, i = lane&15;
  const int base = b*1024 + (m>>3)*32 + (m&7);
  const int pi = base + (i>>2)*256 + (i&3)*8;

  float q[28];
  ld28(qkv + pi*672 + 112 + h*28, q, SCALE_Q);

  float s[16];
  const float* pr = pos2 + (h*16+i)*16;
#pragma unroll
  for (int j4=0;j4<4;j4++){
    f32x4 pv = *(const f32x4*)(pr + j4*4);
    s[j4*4+0]=pv[0]; s[j4*4+1]=pv[1]; s[j4*4+2]=pv[2]; s[j4*4+3]=pv[3];
  }
#pragma unroll
  for (int j=0;j<16;j++){
    const int pj_ = base + (j>>2)*256 + (j&3)*8;
    float kk[28];
    ld28(qkv + pj_*672 + 336 + h*28, kk, 1.0f);
    float a=0.f;
#pragma unroll
    for (int u=0;u<28;u++) a += q[u]*kk[u];
    s[j] += a;
  }
  float mx = s[0];
#pragma unroll
  for (int j=1;j<16;j++) mx = fmaxf(mx, s[j]);
  float sum = 0.f;
#pragma unroll
  for (int j=0;j<16;j++){ float e = __expf(s[j]-mx); s[j]=e; sum+=e; }
  const float inv = 1.f/sum;

  float out[28];
#pragma unroll
  for (int u=0;u<28;u++) out[u]=0.f;
#pragma unroll
  for (int j=0;j<16;j++){
    const int pj_ = base + (j>>2)*256 + (j&3)*8;
    float vv[28];
    ld28(qkv + pj_*672 + 560 + h*28, vv, 1.0f);
    const float pj = s[j];
#pragma unroll
    for (int u=0;u<28;u++) out[u] += pj*vv[u];
  }
  u16* op = attnout + pi*224 + 112 + h*28;
#pragma unroll
  for (int u=0;u<7;u++){
    u32x2 wv;
    wv[0] = (u32)f2bf(out[u*4+0]*inv) | ((u32)f2bf(out[u*4+1]*inv)<<16);
    wv[1] = (u32)f2bf(out[u*4+2]*inv) | ((u32)f2bf(out[u*4+3]*inv)<<16);
    *(u32x2*)(op + u*4) = wv;
  }
}

// ---------------------------------------------------------------------------
extern "C" void kernel_launch(void* const* d_in, const int* in_sizes, int n_in,
                              void* d_out, int out_size, void* d_ws, size_t ws_size,
                              hipStream_t stream) {
  const float* x    = (const float*)d_in[0];
  const float* pos1 = (const float*)d_in[1];
  const float* pos2 = (const float*)d_in[2];
  const float* Wq   = (const float*)d_in[3];
  const float* Wkv  = (const float*)d_in[4];
  const float* Wout = (const float*)d_in[5];
  const float* bout = (const float*)d_in[6];
  const float* wr   = (const float*)d_in[7];
  const float* br   = (const float*)d_in[8];
  const float* w1   = (const float*)d_in[9];
  const float* b1   = (const float*)d_in[10];
  const float* w2   = (const float*)d_in[11];
  const float* b2   = (const float*)d_in[12];
  const float* w3   = (const float*)d_in[13];
  const float* b3   = (const float*)d_in[14];

  char* ws = (char*)d_ws;
  // sizes (bytes)
  const size_t PADSZ = 73984ull*224*2;          // 33,144,832
  const size_t FLATS = 65536ull*224*2;          // 29,360,128
  u16* xpad   = (u16*)(ws);                     // [0, 33.14M)   dead after fused conv
  u16* oApad  = (u16*)(ws + PADSZ);             // [33.1, 66.3M) dead after conv2
  u16* oBpad  = (u16*)(ws + 2*PADSZ);           // [66.3, 99.4M) dead after conv3
  u16* x1bf   = (u16*)(ws + 3*PADSZ);           // [99.4,128.8M) dead after qkv gemm
  u16* convW  = (u16*)(ws + 3*PADSZ + FLATS);   // weights at [128.8,132.9M)
  u16* WqkvT  = convW + 4*451584;
  u16* WoutT  = WqkvT + 672*224;
  u16* qkv     = (u16*)(ws);                    // [0, 88.1M)   after convs done
  u16* attnout = (u16*)(ws + 88080384);         // [88.1,117.4M) after qkv read
  float* dout  = (float*)d_out;

  pack_k<<<8036, 256, 0, stream>>>(Wq, Wkv, Wout, wr, w1, w2, w3, WqkvT, WoutT, convW);
  prep_k<<<8092, 256, 0, stream>>>(x, x1bf, xpad, oApad, oBpad);

  // conv chain: fused(convr->d_out ch448 f32 | conv1->oApad), conv2, conv3(+res)
  gemm_k<M_FUSED><<<dim3(256,2), 512, 0, stream>>>(xpad,  convW,          br, b1, nullptr, oApad, dout);
  gemm_k<M_C2  ><<<dim3(256,1), 512, 0, stream>>>(oApad, convW+2*451584, b2, nullptr, nullptr, oBpad, nullptr);
  gemm_k<M_C3  ><<<dim3(256,1), 512, 0, stream>>>(oBpad, convW+3*451584, b3, nullptr, nullptr, nullptr, dout);

  // attention: qkv gemm, two attn branches, out-proj
  gemm_k<M_QKV ><<<dim3(256,3), 512, 0, stream>>>(x1bf, WqkvT, nullptr, nullptr, qkv, nullptr, nullptr);
  attn1_k<<<1024, 256, 0, stream>>>(qkv, pos1, attnout);
  attn2_k<<<1024, 256, 0, stream>>>(qkv, pos2, attnout);
  gemm_k<M_OUT ><<<dim3(256,2), 512, 0, stream>>>(attnout, WoutT, bout, nullptr, nullptr, nullptr, dout);
}

// Round 6
// 529.925 us; speedup vs baseline: 1.1572x; 1.1572x over previous
//
#include <hip/hip_runtime.h>

typedef unsigned short u16;
typedef unsigned int   u32;
typedef __attribute__((ext_vector_type(4))) float  f32x4;
typedef __attribute__((ext_vector_type(8))) short  s16x8;
typedef __attribute__((ext_vector_type(8))) __bf16 bf16x8;
typedef __attribute__((ext_vector_type(2))) u32    u32x2;

#define DEV __device__ __forceinline__
#define SCALE_Q 0.1889822365046136f   // 28^-0.5

DEV float bf2f(u16 u){ u32 x = ((u32)u)<<16; float f; __builtin_memcpy(&f,&x,4); return f; }
DEV u16   f2bf(float f){ u32 x; __builtin_memcpy(&x,&f,4); return (u16)((x + 0x7fffu + ((x>>16)&1u))>>16); }

DEV s16x8 cvt8(const float* __restrict__ src){
  f32x4 f0 = *(const f32x4*)src, f1 = *(const f32x4*)(src+4);
  bf16x8 b;
  b[0]=(__bf16)f0[0]; b[1]=(__bf16)f0[1]; b[2]=(__bf16)f0[2]; b[3]=(__bf16)f0[3];
  b[4]=(__bf16)f1[0]; b[5]=(__bf16)f1[1]; b[6]=(__bf16)f1[2]; b[7]=(__bf16)f1[3];
  return __builtin_bit_cast(s16x8, b);
}

// async global->LDS, 16B per lane. LDS dest = wave-uniform base + lane*16.
DEV void gll16(const u16* g, u16* l){
  __builtin_amdgcn_global_load_lds(
      (const __attribute__((address_space(1))) u32*)(const void*)g,
      (__attribute__((address_space(3))) u32*)(void*)l,
      16, 0, 0);
}

DEV void ld28(const u16* __restrict__ p, float* dst, float scale){
#pragma unroll
  for (int j=0;j<7;j++){
    u32x2 w = *(const u32x2*)(p + j*4);
    dst[j*4+0] = bf2f((u16)(w[0]&0xffffu))*scale;
    dst[j*4+1] = bf2f((u16)(w[0]>>16))*scale;
    dst[j*4+2] = bf2f((u16)(w[1]&0xffffu))*scale;
    dst[j*4+3] = bf2f((u16)(w[1]>>16))*scale;
  }
}

// ---------------------------------------------------------------------------
// pack_k: f32 weights -> bf16 packed.
//  WqkvT [672][224], WoutT [448][224], convW [4][224][2016] ([conv][co][tap*224+ci], kd=1)
// ---------------------------------------------------------------------------
__global__ void pack_k(const float* __restrict__ Wq, const float* __restrict__ Wkv,
                       const float* __restrict__ Wout,
                       const float* __restrict__ wr, const float* __restrict__ w1,
                       const float* __restrict__ w2, const float* __restrict__ w3,
                       u16* __restrict__ WqkvT, u16* __restrict__ WoutT,
                       u16* __restrict__ convW)
{
  int idx = blockIdx.x*256 + threadIdx.x;
  if (idx < 150528) {
    int nn = idx/224, k = idx - nn*224;
    float v;
    if (nn < 224)      v = Wq [k*224 + nn];
    else if (nn < 448) v = Wkv[k*448 + (nn-224)];
    else               v = Wkv[k*448 + (nn-448) + 224];
    WqkvT[idx] = f2bf(v);
  } else if (idx < 250880) {
    int j = idx - 150528;
    int nn = j/224, k = j - nn*224;
    WoutT[j] = f2bf(Wout[k*448 + nn]);
  } else {
    int j = idx - 250880;
    int cv = j/451584, rem = j - cv*451584;
    int co = rem/2016, kk = rem - co*2016;
    int tap = kk/224, ci = kk - tap*224;
    const float* w = (cv==0)?wr:(cv==1)?w1:(cv==2)?w2:w3;
    convW[j] = f2bf(w[(co*224 + ci)*27 + 9 + tap]);
  }
}

// ---------------------------------------------------------------------------
// prep_k: x(f32,[65536][448]) -> x1bf (bf16 flat [65536][224])
//         and xpad (bf16 padded [64][34][34][224], zero borders);
//         also zero-borders oApad/oBpad.
// ---------------------------------------------------------------------------
__global__ void prep_k(const float* __restrict__ x, u16* __restrict__ x1bf,
                       u16* __restrict__ xpad, u16* __restrict__ oApad,
                       u16* __restrict__ oBpad)
{
  int idx = blockIdx.x*256 + threadIdx.x;   // 8092*256 = 2,071,552 = 73984*28
  int pp = idx/28, c8 = idx - pp*28;
  int b = pp/1156, rem = pp - b*1156, y = rem/34, xx = rem - y*34;
  int c0 = c8*8;
  if (y>=1 && y<=32 && xx>=1 && xx<=32){
    int p = (b*32 + y-1)*32 + (xx-1);
    *(s16x8*)(x1bf + p*224 + c0) = cvt8(x + p*448 + c0);
    *(s16x8*)(xpad + pp*224 + c0) = cvt8(x + p*448 + 224 + c0);
  } else {
    const s16x8 z = {0,0,0,0,0,0,0,0};
    *(s16x8*)(xpad  + pp*224 + c0) = z;
    *(s16x8*)(oApad + pp*224 + c0) = z;
    *(s16x8*)(oBpad + pp*224 + c0) = z;
  }
}

// ---------------------------------------------------------------------------
// GEMM: C[65536 x 224-per-nb] = A[65536 x K] * Bt^T (Bt [N][K] bf16).
// BM=128, BN=224, BK=32, 512 thr (8 waves 4Mx2N), wave tile 32x112 (2x7 frags).
// global_load_lds staging, double-buffered LDS (44 KB -> 2 blocks/CU),
// one barrier per K-step; inter-block TLP hides the vmcnt drain (m97 mechanism).
// Chunk mapping (16B chunks of a [R][32] bf16 tile): chunk c -> row c>>2,
// col (c&3)*8. Thread t stages A chunk t and B chunks t and (t<384) 512+t.
// ---------------------------------------------------------------------------
enum { M_FUSED=0, M_C2=1, M_C3=2, M_QKV=3, M_OUT=4 };

template<int MODE>
__global__ __launch_bounds__(512,4) void gemm_k(
    const u16* __restrict__ A, const u16* __restrict__ Bt,
    const float* __restrict__ bias0, const float* __restrict__ bias1,
    u16* __restrict__ outA, u16* __restrict__ outB, float* __restrict__ outF)
{
  constexpr bool CONV = (MODE==M_FUSED || MODE==M_C2 || MODE==M_C3);
  constexpr int KTOT = CONV ? 2016 : 224;
  constexpr int KS   = KTOT/32;

  __shared__ __align__(16) u16 Als[2][128*32];   // 16 KB
  __shared__ __align__(16) u16 Bls[2][224*32];   // 28 KB

  const int t  = threadIdx.x;
  const int bm = blockIdx.x, nb = blockIdx.y;
  const int lane = t&63, lr = lane&15, lg = lane>>4;
  const int w = t>>6, wm = w>>1, wn = w&1;

  // ---- staging source addresses (chunk c -> row c>>2, col (c&3)*8) ----
  const int arow = t>>2, acol8 = (t&3)*8;
  const int p0 = bm*128 + arow;
  int PP0 = 0;
  if constexpr (CONV) PP0 = ((p0>>10)*34 + ((p0>>5)&31) + 1)*34 + (p0&31) + 1;
  const int Bb0 = (nb*224 +       arow)*KTOT + acol8;   // chunk t
  const int Bb1 = (nb*224 + 128 + arow)*KTOT + acol8;   // chunk 512+t (t<384)

  // wave-uniform LDS dest bases (u16 units; chunk c at byte c*16)
  u16* aBase[2] = { &Als[0][0] + w*512, &Als[1][0] + w*512 };
  u16* bBase[2] = { &Bls[0][0] + w*512, &Bls[1][0] + w*512 };

  auto STAGE = [&](int buf, int ks){
    if constexpr (CONV){
      const int tap = ks/7, kc = ks - tap*7;
      const int ty = tap/3, tx = tap - ty*3;
      const int toff = (ty-1)*34 + (tx-1);
      gll16(A + (PP0+toff)*224 + kc*32 + acol8, aBase[buf]);
    } else {
      gll16(A + p0*224 + ks*32 + acol8, aBase[buf]);
    }
    gll16(Bt + Bb0 + ks*32, bBase[buf]);
    if (w < 6) gll16(Bt + Bb1 + ks*32, bBase[buf] + 4096);
  };

  f32x4 acc[2][7];
  { f32x4 zf = {0.f,0.f,0.f,0.f};
#pragma unroll
    for (int i=0;i<2;i++)
#pragma unroll
      for (int j=0;j<7;j++) acc[i][j] = zf; }

  STAGE(0, 0);
  __syncthreads();   // vmcnt(0) drained: buf0 ready

  for (int ks=0; ks<KS; ++ks){
    const int cur = ks&1;
    if (ks+1 < KS) STAGE(cur^1, ks+1);   // prefetch overlaps this iter's compute

    const u16* Ac = &Als[cur][0];
    const u16* Bc = &Bls[cur][0];
    bf16x8 af[2], bfv[7];
#pragma unroll
    for (int mi=0; mi<2; ++mi)
      af[mi] = *(const bf16x8*)(Ac + (wm*32 + mi*16 + lr)*32 + lg*8);
#pragma unroll
    for (int ni=0; ni<7; ++ni)
      bfv[ni] = *(const bf16x8*)(Bc + (wn*112 + ni*16 + lr)*32 + lg*8);

#pragma unroll
    for (int ni=0; ni<7; ++ni)
#pragma unroll
      for (int mi=0; mi<2; ++mi)
        acc[mi][ni] = __builtin_amdgcn_mfma_f32_16x16x32_bf16(af[mi], bfv[ni], acc[mi][ni], 0,0,0);

    __syncthreads();   // prefetch landed + all reads of cur done
  }

  // ---- epilogue ----
  const float* bs;
  if constexpr (MODE==M_FUSED) bs = (nb==0) ? bias0 : bias1;
  else bs = bias0;

#pragma unroll
  for (int mi=0; mi<2; ++mi){
    const int rbase = bm*128 + wm*32 + mi*16 + lg*4;
#pragma unroll
    for (int ni=0; ni<7; ++ni){
      const int col = wn*112 + ni*16 + lr;
#pragma unroll
      for (int r=0;r<4;r++){
        const int row = rbase + r;
        float v = acc[mi][ni][r];
        if constexpr (MODE==M_FUSED){
          v = fmaxf(v + bs[col], 0.f);
          if (nb==0){
            outF[row*672 + 448 + col] = v;         // res (f32, lives in d_out)
          } else {
            const int pp = ((row>>10)*34 + ((row>>5)&31) + 1)*34 + (row&31) + 1;
            outB[pp*224 + col] = f2bf(v);          // conv1 out (padded)
          }
        } else if constexpr (MODE==M_C2){
          v = fmaxf(v + bs[col], 0.f);
          const int pp = ((row>>10)*34 + ((row>>5)&31) + 1)*34 + (row&31) + 1;
          outB[pp*224 + col] = f2bf(v);            // conv2 out (padded)
        } else if constexpr (MODE==M_C3){
          v = fmaxf(v + bs[col], 0.f);
          const int o = row*672 + 448 + col;
          outF[o] = v + outF[o];                   // X2S = relu(conv3)+res
        } else if constexpr (MODE==M_QKV){
          outA[row*672 + nb*224 + col] = f2bf(v);  // qkv bf16 ws
        } else {                                   // M_OUT
          outF[row*672 + nb*224 + col] = v + bs[nb*224 + col];
        }
      }
    }
  }
}

// ---------------------------------------------------------------------------
// Branch-1 attention
// ---------------------------------------------------------------------------
__global__ __launch_bounds__(256,2) void attn1_k(const u16* __restrict__ qkv,
    const float* __restrict__ pos1, u16* __restrict__ attnout)
{
  __shared__ __align__(16) float KL[64][112];
  __shared__ __align__(16) float VL[64][112];
  const int t = threadIdx.x;
  const int b = blockIdx.x>>4, n = blockIdx.x&15;
  const int base = b*1024 + (n>>2)*256 + (n&3)*8;
  {
    const int r = t>>2, part = t&3;
    const int pr_ = base + (r>>3)*32 + (r&7);
    const u16* kp = qkv + pr_*672 + 224 + part*28;
    const u16* vp = kp + 224;
#pragma unroll
    for (int j=0;j<7;j++){
      u32x2 kk = *(const u32x2*)(kp + j*4);
      u32x2 vv = *(const u32x2*)(vp + j*4);
      const int c = part*28 + j*4;
      KL[r][c+0]=bf2f((u16)(kk[0]&0xffffu)); KL[r][c+1]=bf2f((u16)(kk[0]>>16));
      KL[r][c+2]=bf2f((u16)(kk[1]&0xffffu)); KL[r][c+3]=bf2f((u16)(kk[1]>>16));
      VL[r][c+0]=bf2f((u16)(vv[0]&0xffffu)); VL[r][c+1]=bf2f((u16)(vv[0]>>16));
      VL[r][c+2]=bf2f((u16)(vv[1]&0xffffu)); VL[r][c+3]=bf2f((u16)(vv[1]>>16));
    }
  }
  __syncthreads();

  const int h = t>>6, i = t&63;
  const int pi = base + (i>>3)*32 + (i&7);
  float q[28];
  ld28(qkv + pi*672 + h*28, q, SCALE_Q);

  float s[64];
  const float* pr = pos1 + (h*64+i)*64;
#pragma unroll
  for (int j4=0;j4<16;j4++){
    f32x4 pv = *(const f32x4*)(pr + j4*4);
    s[j4*4+0]=pv[0]; s[j4*4+1]=pv[1]; s[j4*4+2]=pv[2]; s[j4*4+3]=pv[3];
  }
  const int c0 = h*28;
#pragma unroll
  for (int j=0;j<64;j++){
    const f32x4* kr = (const f32x4*)&KL[j][c0];
    float a0=0.f,a1=0.f,a2=0.f,a3=0.f;
#pragma unroll
    for (int u=0;u<7;u++){
      f32x4 kv = kr[u];
      a0 += q[u*4+0]*kv[0]; a1 += q[u*4+1]*kv[1];
      a2 += q[u*4+2]*kv[2]; a3 += q[u*4+3]*kv[3];
    }
    s[j] += (a0+a1)+(a2+a3);
  }
  float mx = s[0];
#pragma unroll
  for (int j=1;j<64;j++) mx = fmaxf(mx, s[j]);
  float sum = 0.f;
#pragma unroll
  for (int j=0;j<64;j++){ float e = __expf(s[j]-mx); s[j]=e; sum+=e; }
  const float inv = 1.f/sum;

  float out[28];
#pragma unroll
  for (int u=0;u<28;u++) out[u]=0.f;
#pragma unroll
  for (int j=0;j<64;j++){
    const float pj = s[j];
    const f32x4* vr = (const f32x4*)&VL[j][c0];
#pragma unroll
    for (int u=0;u<7;u++){
      f32x4 vv = vr[u];
      out[u*4+0] += pj*vv[0]; out[u*4+1] += pj*vv[1];
      out[u*4+2] += pj*vv[2]; out[u*4+3] += pj*vv[3];
    }
  }
  u16* op = attnout + pi*224 + h*28;
#pragma unroll
  for (int u=0;u<7;u++){
    u32x2 wv;
    wv[0] = (u32)f2bf(out[u*4+0]*inv) | ((u32)f2bf(out[u*4+1]*inv)<<16);
    wv[1] = (u32)f2bf(out[u*4+2]*inv) | ((u32)f2bf(out[u*4+3]*inv)<<16);
    *(u32x2*)(op + u*4) = wv;
  }
}

// ---------------------------------------------------------------------------
// Branch-2 attention
// ---------------------------------------------------------------------------
__global__ __launch_bounds__(256,1) void attn2_k(const u16* __restrict__ qkv,
    const float* __restrict__ pos2, u16* __restrict__ attnout)
{
  const int t = threadIdx.x;
  const int b = blockIdx.x>>4, mg = blockIdx.x&15;
  const int m = mg*4 + (t>>6);
  const int lane = t&63, h = lane>>4, i = lane&15;
  const int base = b*1024 + (m>>3)*32 + (m&7);
  const int pi = base + (i>>2)*256 + (i&3)*8;

  float q[28];
  ld28(qkv + pi*672 + 112 + h*28, q, SCALE_Q);

  float s[16];
  const float* pr = pos2 + (h*16+i)*16;
#pragma unroll
  for (int j4=0;j4<4;j4++){
    f32x4 pv = *(const f32x4*)(pr + j4*4);
    s[j4*4+0]=pv[0]; s[j4*4+1]=pv[1]; s[j4*4+2]=pv[2]; s[j4*4+3]=pv[3];
  }
#pragma unroll
  for (int j=0;j<16;j++){
    const int pj_ = base + (j>>2)*256 + (j&3)*8;
    float kk[28];
    ld28(qkv + pj_*672 + 336 + h*28, kk, 1.0f);
    float a=0.f;
#pragma unroll
    for (int u=0;u<28;u++) a += q[u]*kk[u];
    s[j] += a;
  }
  float mx = s[0];
#pragma unroll
  for (int j=1;j<16;j++) mx = fmaxf(mx, s[j]);
  float sum = 0.f;
#pragma unroll
  for (int j=0;j<16;j++){ float e = __expf(s[j]-mx); s[j]=e; sum+=e; }
  const float inv = 1.f/sum;

  float out[28];
#pragma unroll
  for (int u=0;u<28;u++) out[u]=0.f;
#pragma unroll
  for (int j=0;j<16;j++){
    const int pj_ = base + (j>>2)*256 + (j&3)*8;
    float vv[28];
    ld28(qkv + pj_*672 + 560 + h*28, vv, 1.0f);
    const float pj = s[j];
#pragma unroll
    for (int u=0;u<28;u++) out[u] += pj*vv[u];
  }
  u16* op = attnout + pi*224 + 112 + h*28;
#pragma unroll
  for (int u=0;u<7;u++){
    u32x2 wv;
    wv[0] = (u32)f2bf(out[u*4+0]*inv) | ((u32)f2bf(out[u*4+1]*inv)<<16);
    wv[1] = (u32)f2bf(out[u*4+2]*inv) | ((u32)f2bf(out[u*4+3]*inv)<<16);
    *(u32x2*)(op + u*4) = wv;
  }
}

// ---------------------------------------------------------------------------
extern "C" void kernel_launch(void* const* d_in, const int* in_sizes, int n_in,
                              void* d_out, int out_size, void* d_ws, size_t ws_size,
                              hipStream_t stream) {
  const float* x    = (const float*)d_in[0];
  const float* pos1 = (const float*)d_in[1];
  const float* pos2 = (const float*)d_in[2];
  const float* Wq   = (const float*)d_in[3];
  const float* Wkv  = (const float*)d_in[4];
  const float* Wout = (const float*)d_in[5];
  const float* bout = (const float*)d_in[6];
  const float* wr   = (const float*)d_in[7];
  const float* br   = (const float*)d_in[8];
  const float* w1   = (const float*)d_in[9];
  const float* b1   = (const float*)d_in[10];
  const float* w2   = (const float*)d_in[11];
  const float* b2   = (const float*)d_in[12];
  const float* w3   = (const float*)d_in[13];
  const float* b3   = (const float*)d_in[14];

  char* ws = (char*)d_ws;
  const size_t PADSZ = 73984ull*224*2;          // 33,144,832
  const size_t FLATS = 65536ull*224*2;          // 29,360,128
  u16* xpad   = (u16*)(ws);                     // dead after fused conv
  u16* oApad  = (u16*)(ws + PADSZ);             // dead after conv2
  u16* oBpad  = (u16*)(ws + 2*PADSZ);           // dead after conv3
  u16* x1bf   = (u16*)(ws + 3*PADSZ);           // dead after qkv gemm
  u16* convW  = (u16*)(ws + 3*PADSZ + FLATS);
  u16* WqkvT  = convW + 4*451584;
  u16* WoutT  = WqkvT + 672*224;
  u16* qkv     = (u16*)(ws);                    // after convs done
  u16* attnout = (u16*)(ws + 88080384);
  float* dout  = (float*)d_out;

  pack_k<<<8036, 256, 0, stream>>>(Wq, Wkv, Wout, wr, w1, w2, w3, WqkvT, WoutT, convW);
  prep_k<<<8092, 256, 0, stream>>>(x, x1bf, xpad, oApad, oBpad);

  // conv chain: fused(convr->d_out ch448 f32 | conv1->oApad), conv2, conv3(+res)
  gemm_k<M_FUSED><<<dim3(512,2), 512, 0, stream>>>(xpad,  convW,          br, b1, nullptr, oApad, dout);
  gemm_k<M_C2  ><<<dim3(512,1), 512, 0, stream>>>(oApad, convW+2*451584, b2, nullptr, nullptr, oBpad, nullptr);
  gemm_k<M_C3  ><<<dim3(512,1), 512, 0, stream>>>(oBpad, convW+3*451584, b3, nullptr, nullptr, nullptr, dout);

  // attention: qkv gemm, two attn branches, out-proj
  gemm_k<M_QKV ><<<dim3(512,3), 512, 0, stream>>>(x1bf, WqkvT, nullptr, nullptr, qkv, nullptr, nullptr);
  attn1_k<<<1024, 256, 0, stream>>>(qkv, pos1, attnout);
  attn2_k<<<1024, 256, 0, stream>>>(qkv, pos2, attnout);
  gemm_k<M_OUT ><<<dim3(512,2), 512, 0, stream>>>(attnout, WoutT, bout, nullptr, nullptr, nullptr, dout);
}

// Round 7
// 510.616 us; speedup vs baseline: 1.2010x; 1.0378x over previous
//
#include <hip/hip_runtime.h>

typedef unsigned short u16;
typedef unsigned int   u32;
typedef __attribute__((ext_vector_type(4))) float  f32x4;
typedef __attribute__((ext_vector_type(8))) short  s16x8;
typedef __attribute__((ext_vector_type(8))) __bf16 bf16x8;
typedef __attribute__((ext_vector_type(2))) u32    u32x2;

#define DEV __device__ __forceinline__
#define SCALE_Q 0.1889822365046136f   // 28^-0.5

DEV float bf2f(u16 u){ u32 x = ((u32)u)<<16; float f; __builtin_memcpy(&f,&x,4); return f; }
DEV u16   f2bf(float f){ u32 x; __builtin_memcpy(&x,&f,4); return (u16)((x + 0x7fffu + ((x>>16)&1u))>>16); }

DEV s16x8 cvt8(const float* __restrict__ src){
  f32x4 f0 = *(const f32x4*)src, f1 = *(const f32x4*)(src+4);
  bf16x8 b;
  b[0]=(__bf16)f0[0]; b[1]=(__bf16)f0[1]; b[2]=(__bf16)f0[2]; b[3]=(__bf16)f0[3];
  b[4]=(__bf16)f1[0]; b[5]=(__bf16)f1[1]; b[6]=(__bf16)f1[2]; b[7]=(__bf16)f1[3];
  return __builtin_bit_cast(s16x8, b);
}

// async global->LDS, 16B per lane. LDS dest = wave-uniform base + lane*16.
DEV void gll16(const u16* g, u16* l){
  __builtin_amdgcn_global_load_lds(
      (const __attribute__((address_space(1))) u32*)(const void*)g,
      (__attribute__((address_space(3))) u32*)(void*)l,
      16, 0, 0);
}

DEV void ld28(const u16* __restrict__ p, float* dst, float scale){
#pragma unroll
  for (int j=0;j<7;j++){
    u32x2 w = *(const u32x2*)(p + j*4);
    dst[j*4+0] = bf2f((u16)(w[0]&0xffffu))*scale;
    dst[j*4+1] = bf2f((u16)(w[0]>>16))*scale;
    dst[j*4+2] = bf2f((u16)(w[1]&0xffffu))*scale;
    dst[j*4+3] = bf2f((u16)(w[1]>>16))*scale;
  }
}

// ---------------------------------------------------------------------------
// pack_k: f32 weights -> bf16 packed.
//  WqkvT [672][224], WoutT [448][224], convW [4][224][2016] ([conv][co][tap*224+ci], kd=1)
// ---------------------------------------------------------------------------
__global__ void pack_k(const float* __restrict__ Wq, const float* __restrict__ Wkv,
                       const float* __restrict__ Wout,
                       const float* __restrict__ wr, const float* __restrict__ w1,
                       const float* __restrict__ w2, const float* __restrict__ w3,
                       u16* __restrict__ WqkvT, u16* __restrict__ WoutT,
                       u16* __restrict__ convW)
{
  int idx = blockIdx.x*256 + threadIdx.x;
  if (idx < 150528) {
    int nn = idx/224, k = idx - nn*224;
    float v;
    if (nn < 224)      v = Wq [k*224 + nn];
    else if (nn < 448) v = Wkv[k*448 + (nn-224)];
    else               v = Wkv[k*448 + (nn-448) + 224];
    WqkvT[idx] = f2bf(v);
  } else if (idx < 250880) {
    int j = idx - 150528;
    int nn = j/224, k = j - nn*224;
    WoutT[j] = f2bf(Wout[k*448 + nn]);
  } else {
    int j = idx - 250880;
    int cv = j/451584, rem = j - cv*451584;
    int co = rem/2016, kk = rem - co*2016;
    int tap = kk/224, ci = kk - tap*224;
    const float* w = (cv==0)?wr:(cv==1)?w1:(cv==2)?w2:w3;
    convW[j] = f2bf(w[(co*224 + ci)*27 + 9 + tap]);
  }
}

// ---------------------------------------------------------------------------
// prep_k: x(f32,[65536][448]) -> x1bf (bf16 flat [65536][224])
//         and xpad (bf16 padded [64][34][34][224], zero borders);
//         also zero-borders oApad/oBpad.
// ---------------------------------------------------------------------------
__global__ void prep_k(const float* __restrict__ x, u16* __restrict__ x1bf,
                       u16* __restrict__ xpad, u16* __restrict__ oApad,
                       u16* __restrict__ oBpad)
{
  int idx = blockIdx.x*256 + threadIdx.x;   // 8092*256 = 2,071,552 = 73984*28
  int pp = idx/28, c8 = idx - pp*28;
  int b = pp/1156, rem = pp - b*1156, y = rem/34, xx = rem - y*34;
  int c0 = c8*8;
  if (y>=1 && y<=32 && xx>=1 && xx<=32){
    int p = (b*32 + y-1)*32 + (xx-1);
    *(s16x8*)(x1bf + p*224 + c0) = cvt8(x + p*448 + c0);
    *(s16x8*)(xpad + pp*224 + c0) = cvt8(x + p*448 + 224 + c0);
  } else {
    const s16x8 z = {0,0,0,0,0,0,0,0};
    *(s16x8*)(xpad  + pp*224 + c0) = z;
    *(s16x8*)(oApad + pp*224 + c0) = z;
    *(s16x8*)(oBpad + pp*224 + c0) = z;
  }
}

// ---------------------------------------------------------------------------
// GEMM: C[65536 x 224-per-nb] = A[65536 x K] * Bt^T (Bt [N][K] bf16).
// BM=128, BN=224, BK=32, 512 thr (8 waves 4Mx2N), wave tile 32x112 (2x7 frags).
// global_load_lds staging, double-buffered LDS (44 KB -> 2 blocks/CU),
// one barrier per K-step; inter-block TLP hides the vmcnt drain.
//
// LDS granule swizzle (bank-conflict fix, both-sides involution):
//   16B-granule g holds tile element (row = g>>2, q = ((g&3) - ((g>>4)&3))&3).
//   Stage: thread t writes granule t linearly; its SOURCE granule column is
//   qsrc = ((t&3) - ((t>>4)&3))&3.  Read (row r, col-granule lg) from
//   granule r*4 + ((lg + (r>>2))&3).  Quarter-wave lanes then spread 2-way
//   over all 8 granule-positions-mod-128B (2-way = free) instead of 8-way.
//
// Conv K-order is tap-INNER (tap=ks%9, kc=ks/9): 9 consecutive steps reuse
// the same activation rows (L2-hot) -> FETCH drops ~2.5x.
// XCD swizzle: bm = (x&7)*64 + x>>3 (grid.x=512) -> each XCD owns a
// contiguous pixel range; both nb panels share A in its L2.
// ---------------------------------------------------------------------------
enum { M_FUSED=0, M_C2=1, M_C3=2, M_QKV=3, M_OUT=4 };

template<int MODE>
__global__ __launch_bounds__(512,4) void gemm_k(
    const u16* __restrict__ A, const u16* __restrict__ Bt,
    const float* __restrict__ bias0, const float* __restrict__ bias1,
    u16* __restrict__ outA, u16* __restrict__ outB, float* __restrict__ outF)
{
  constexpr bool CONV = (MODE==M_FUSED || MODE==M_C2 || MODE==M_C3);
  constexpr int KTOT = CONV ? 2016 : 224;
  constexpr int KS   = KTOT/32;

  __shared__ __align__(16) u16 Als[2][128*32];   // 16 KB
  __shared__ __align__(16) u16 Bls[2][224*32];   // 28 KB

  const int t  = threadIdx.x;
  const int bmRaw = blockIdx.x, nb = blockIdx.y;
  const int bm = ((bmRaw&7)<<6) + (bmRaw>>3);    // XCD-contiguous (grid.x=512)
  const int lane = t&63, lr = lane&15, lg = lane>>4;
  const int w = t>>6, wm = w>>1, wn = w&1;

  // ---- staging source addresses (granule t; inverse-swizzled source col) ----
  const int arow = t>>2;
  const int qsrc = ((t&3) - ((t>>4)&3)) & 3;
  const int acol8 = qsrc*8;
  const int p0 = bm*128 + arow;
  int PP0 = 0;
  if constexpr (CONV) PP0 = ((p0>>10)*34 + ((p0>>5)&31) + 1)*34 + (p0&31) + 1;
  const int Bb0 = (nb*224 +       arow)*KTOT + acol8;   // granule t
  const int Bb1 = (nb*224 + 128 + arow)*KTOT + acol8;   // granule 512+t (t<384)

  // wave-uniform LDS dest bases (u16 units; granule c at byte c*16)
  u16* aBase[2] = { &Als[0][0] + w*512, &Als[1][0] + w*512 };
  u16* bBase[2] = { &Bls[0][0] + w*512, &Bls[1][0] + w*512 };

  auto STAGE = [&](int buf, int ks){
    if constexpr (CONV){
      const int kc  = ks/9;
      const int tap = ks - kc*9;          // tap-inner: rows stay L2-hot
      const int ty = tap/3, tx = tap - ty*3;
      const int toff = (ty-1)*34 + (tx-1);
      const int koff = tap*224 + kc*32;
      gll16(A + (PP0+toff)*224 + kc*32 + acol8, aBase[buf]);
      gll16(Bt + Bb0 + koff, bBase[buf]);
      if (w < 6) gll16(Bt + Bb1 + koff, bBase[buf] + 4096);
    } else {
      gll16(A + p0*224 + ks*32 + acol8, aBase[buf]);
      gll16(Bt + Bb0 + ks*32, bBase[buf]);
      if (w < 6) gll16(Bt + Bb1 + ks*32, bBase[buf] + 4096);
    }
  };

  f32x4 acc[2][7];
  { f32x4 zf = {0.f,0.f,0.f,0.f};
#pragma unroll
    for (int i=0;i<2;i++)
#pragma unroll
      for (int j=0;j<7;j++) acc[i][j] = zf; }

  STAGE(0, 0);
  __syncthreads();   // vmcnt(0) drained: buf0 ready

  for (int ks=0; ks<KS; ++ks){
    const int cur = ks&1;
    if (ks+1 < KS) STAGE(cur^1, ks+1);   // prefetch overlaps this iter's compute

    const u16* Ac = &Als[cur][0];
    const u16* Bc = &Bls[cur][0];
    bf16x8 af[2], bfv[7];
#pragma unroll
    for (int mi=0; mi<2; ++mi){
      const int row = wm*32 + mi*16 + lr;
      af[mi] = *(const bf16x8*)(Ac + row*32 + ((lg + (row>>2))&3)*8);
    }
#pragma unroll
    for (int ni=0; ni<7; ++ni){
      const int row = wn*112 + ni*16 + lr;
      bfv[ni] = *(const bf16x8*)(Bc + row*32 + ((lg + (row>>2))&3)*8);
    }

#pragma unroll
    for (int ni=0; ni<7; ++ni)
#pragma unroll
      for (int mi=0; mi<2; ++mi)
        acc[mi][ni] = __builtin_amdgcn_mfma_f32_16x16x32_bf16(af[mi], bfv[ni], acc[mi][ni], 0,0,0);

    __syncthreads();   // prefetch landed + all reads of cur done
  }

  // ---- epilogue ----
  const float* bs;
  if constexpr (MODE==M_FUSED) bs = (nb==0) ? bias0 : bias1;
  else bs = bias0;

#pragma unroll
  for (int mi=0; mi<2; ++mi){
    const int rbase = bm*128 + wm*32 + mi*16 + lg*4;
#pragma unroll
    for (int ni=0; ni<7; ++ni){
      const int col = wn*112 + ni*16 + lr;
#pragma unroll
      for (int r=0;r<4;r++){
        const int row = rbase + r;
        float v = acc[mi][ni][r];
        if constexpr (MODE==M_FUSED){
          v = fmaxf(v + bs[col], 0.f);
          if (nb==0){
            outF[row*672 + 448 + col] = v;         // res (f32, lives in d_out)
          } else {
            const int pp = ((row>>10)*34 + ((row>>5)&31) + 1)*34 + (row&31) + 1;
            outB[pp*224 + col] = f2bf(v);          // conv1 out (padded)
          }
        } else if constexpr (MODE==M_C2){
          v = fmaxf(v + bs[col], 0.f);
          const int pp = ((row>>10)*34 + ((row>>5)&31) + 1)*34 + (row&31) + 1;
          outB[pp*224 + col] = f2bf(v);            // conv2 out (padded)
        } else if constexpr (MODE==M_C3){
          v = fmaxf(v + bs[col], 0.f);
          const int o = row*672 + 448 + col;
          outF[o] = v + outF[o];                   // X2S = relu(conv3)+res
        } else if constexpr (MODE==M_QKV){
          outA[row*672 + nb*224 + col] = f2bf(v);  // qkv bf16 ws
        } else {                                   // M_OUT
          outF[row*672 + nb*224 + col] = v + bs[nb*224 + col];
        }
      }
    }
  }
}

// ---------------------------------------------------------------------------
// Branch-1 attention
// ---------------------------------------------------------------------------
__global__ __launch_bounds__(256,2) void attn1_k(const u16* __restrict__ qkv,
    const float* __restrict__ pos1, u16* __restrict__ attnout)
{
  __shared__ __align__(16) float KL[64][112];
  __shared__ __align__(16) float VL[64][112];
  const int t = threadIdx.x;
  const int b = blockIdx.x>>4, n = blockIdx.x&15;
  const int base = b*1024 + (n>>2)*256 + (n&3)*8;
  {
    const int r = t>>2, part = t&3;
    const int pr_ = base + (r>>3)*32 + (r&7);
    const u16* kp = qkv + pr_*672 + 224 + part*28;
    const u16* vp = kp + 224;
#pragma unroll
    for (int j=0;j<7;j++){
      u32x2 kk = *(const u32x2*)(kp + j*4);
      u32x2 vv = *(const u32x2*)(vp + j*4);
      const int c = part*28 + j*4;
      KL[r][c+0]=bf2f((u16)(kk[0]&0xffffu)); KL[r][c+1]=bf2f((u16)(kk[0]>>16));
      KL[r][c+2]=bf2f((u16)(kk[1]&0xffffu)); KL[r][c+3]=bf2f((u16)(kk[1]>>16));
      VL[r][c+0]=bf2f((u16)(vv[0]&0xffffu)); VL[r][c+1]=bf2f((u16)(vv[0]>>16));
      VL[r][c+2]=bf2f((u16)(vv[1]&0xffffu)); VL[r][c+3]=bf2f((u16)(vv[1]>>16));
    }
  }
  __syncthreads();

  const int h = t>>6, i = t&63;
  const int pi = base + (i>>3)*32 + (i&7);
  float q[28];
  ld28(qkv + pi*672 + h*28, q, SCALE_Q);

  float s[64];
  const float* pr = pos1 + (h*64+i)*64;
#pragma unroll
  for (int j4=0;j4<16;j4++){
    f32x4 pv = *(const f32x4*)(pr + j4*4);
    s[j4*4+0]=pv[0]; s[j4*4+1]=pv[1]; s[j4*4+2]=pv[2]; s[j4*4+3]=pv[3];
  }
  const int c0 = h*28;
#pragma unroll
  for (int j=0;j<64;j++){
    const f32x4* kr = (const f32x4*)&KL[j][c0];
    float a0=0.f,a1=0.f,a2=0.f,a3=0.f;
#pragma unroll
    for (int u=0;u<7;u++){
      f32x4 kv = kr[u];
      a0 += q[u*4+0]*kv[0]; a1 += q[u*4+1]*kv[1];
      a2 += q[u*4+2]*kv[2]; a3 += q[u*4+3]*kv[3];
    }
    s[j] += (a0+a1)+(a2+a3);
  }
  float mx = s[0];
#pragma unroll
  for (int j=1;j<64;j++) mx = fmaxf(mx, s[j]);
  float sum = 0.f;
#pragma unroll
  for (int j=0;j<64;j++){ float e = __expf(s[j]-mx); s[j]=e; sum+=e; }
  const float inv = 1.f/sum;

  float out[28];
#pragma unroll
  for (int u=0;u<28;u++) out[u]=0.f;
#pragma unroll
  for (int j=0;j<64;j++){
    const float pj = s[j];
    const f32x4* vr = (const f32x4*)&VL[j][c0];
#pragma unroll
    for (int u=0;u<7;u++){
      f32x4 vv = vr[u];
      out[u*4+0] += pj*vv[0]; out[u*4+1] += pj*vv[1];
      out[u*4+2] += pj*vv[2]; out[u*4+3] += pj*vv[3];
    }
  }
  u16* op = attnout + pi*224 + h*28;
#pragma unroll
  for (int u=0;u<7;u++){
    u32x2 wv;
    wv[0] = (u32)f2bf(out[u*4+0]*inv) | ((u32)f2bf(out[u*4+1]*inv)<<16);
    wv[1] = (u32)f2bf(out[u*4+2]*inv) | ((u32)f2bf(out[u*4+3]*inv)<<16);
    *(u32x2*)(op + u*4) = wv;
  }
}

// ---------------------------------------------------------------------------
// Branch-2 attention
// ---------------------------------------------------------------------------
__global__ __launch_bounds__(256,1) void attn2_k(const u16* __restrict__ qkv,
    const float* __restrict__ pos2, u16* __restrict__ attnout)
{
  const int t = threadIdx.x;
  const int b = blockIdx.x>>4, mg = blockIdx.x&15;
  const int m = mg*4 + (t>>6);
  const int lane = t&63, h = lane>>4, i = lane&15;
  const int base = b*1024 + (m>>3)*32 + (m&7);
  const int pi = base + (i>>2)*256 + (i&3)*8;

  float q[28];
  ld28(qkv + pi*672 + 112 + h*28, q, SCALE_Q);

  float s[16];
  const float* pr = pos2 + (h*16+i)*16;
#pragma unroll
  for (int j4=0;j4<4;j4++){
    f32x4 pv = *(const f32x4*)(pr + j4*4);
    s[j4*4+0]=pv[0]; s[j4*4+1]=pv[1]; s[j4*4+2]=pv[2]; s[j4*4+3]=pv[3];
  }
#pragma unroll
  for (int j=0;j<16;j++){
    const int pj_ = base + (j>>2)*256 + (j&3)*8;
    float kk[28];
    ld28(qkv + pj_*672 + 336 + h*28, kk, 1.0f);
    float a=0.f;
#pragma unroll
    for (int u=0;u<28;u++) a += q[u]*kk[u];
    s[j] += a;
  }
  float mx = s[0];
#pragma unroll
  for (int j=1;j<16;j++) mx = fmaxf(mx, s[j]);
  float sum = 0.f;
#pragma unroll
  for (int j=0;j<16;j++){ float e = __expf(s[j]-mx); s[j]=e; sum+=e; }
  const float inv = 1.f/sum;

  float out[28];
#pragma unroll
  for (int u=0;u<28;u++) out[u]=0.f;
#pragma unroll
  for (int j=0;j<16;j++){
    const int pj_ = base + (j>>2)*256 + (j&3)*8;
    float vv[28];
    ld28(qkv + pj_*672 + 560 + h*28, vv, 1.0f);
    const float pj = s[j];
#pragma unroll
    for (int u=0;u<28;u++) out[u] += pj*vv[u];
  }
  u16* op = attnout + pi*224 + 112 + h*28;
#pragma unroll
  for (int u=0;u<7;u++){
    u32x2 wv;
    wv[0] = (u32)f2bf(out[u*4+0]*inv) | ((u32)f2bf(out[u*4+1]*inv)<<16);
    wv[1] = (u32)f2bf(out[u*4+2]*inv) | ((u32)f2bf(out[u*4+3]*inv)<<16);
    *(u32x2*)(op + u*4) = wv;
  }
}

// ---------------------------------------------------------------------------
extern "C" void kernel_launch(void* const* d_in, const int* in_sizes, int n_in,
                              void* d_out, int out_size, void* d_ws, size_t ws_size,
                              hipStream_t stream) {
  const float* x    = (const float*)d_in[0];
  const float* pos1 = (const float*)d_in[1];
  const float* pos2 = (const float*)d_in[2];
  const float* Wq   = (const float*)d_in[3];
  const float* Wkv  = (const float*)d_in[4];
  const float* Wout = (const float*)d_in[5];
  const float* bout = (const float*)d_in[6];
  const float* wr   = (const float*)d_in[7];
  const float* br   = (const float*)d_in[8];
  const float* w1   = (const float*)d_in[9];
  const float* b1   = (const float*)d_in[10];
  const float* w2   = (const float*)d_in[11];
  const float* b2   = (const float*)d_in[12];
  const float* w3   = (const float*)d_in[13];
  const float* b3   = (const float*)d_in[14];

  char* ws = (char*)d_ws;
  const size_t PADSZ = 73984ull*224*2;          // 33,144,832
  const size_t FLATS = 65536ull*224*2;          // 29,360,128
  u16* xpad   = (u16*)(ws);                     // dead after fused conv
  u16* oApad  = (u16*)(ws + PADSZ);             // dead after conv2
  u16* oBpad  = (u16*)(ws + 2*PADSZ);           // dead after conv3
  u16* x1bf   = (u16*)(ws + 3*PADSZ);           // dead after qkv gemm
  u16* convW  = (u16*)(ws + 3*PADSZ + FLATS);
  u16* WqkvT  = convW + 4*451584;
  u16* WoutT  = WqkvT + 672*224;
  u16* qkv     = (u16*)(ws);                    // after convs done
  u16* attnout = (u16*)(ws + 88080384);
  float* dout  = (float*)d_out;

  pack_k<<<8036, 256, 0, stream>>>(Wq, Wkv, Wout, wr, w1, w2, w3, WqkvT, WoutT, convW);
  prep_k<<<8092, 256, 0, stream>>>(x, x1bf, xpad, oApad, oBpad);

  // conv chain: fused(convr->d_out ch448 f32 | conv1->oApad), conv2, conv3(+res)
  gemm_k<M_FUSED><<<dim3(512,2), 512, 0, stream>>>(xpad,  convW,          br, b1, nullptr, oApad, dout);
  gemm_k<M_C2  ><<<dim3(512,1), 512, 0, stream>>>(oApad, convW+2*451584, b2, nullptr, nullptr, oBpad, nullptr);
  gemm_k<M_C3  ><<<dim3(512,1), 512, 0, stream>>>(oBpad, convW+3*451584, b3, nullptr, nullptr, nullptr, dout);

  // attention: qkv gemm, two attn branches, out-proj
  gemm_k<M_QKV ><<<dim3(512,3), 512, 0, stream>>>(x1bf, WqkvT, nullptr, nullptr, qkv, nullptr, nullptr);
  attn1_k<<<1024, 256, 0, stream>>>(qkv, pos1, attnout);
  attn2_k<<<1024, 256, 0, stream>>>(qkv, pos2, attnout);
  gemm_k<M_OUT ><<<dim3(512,2), 512, 0, stream>>>(attnout, WoutT, bout, nullptr, nullptr, nullptr, dout);
}

// Round 8
// 506.741 us; speedup vs baseline: 1.2101x; 1.0076x over previous
//
#include <hip/hip_runtime.h>

typedef unsigned short u16;
typedef unsigned int   u32;
typedef __attribute__((ext_vector_type(4))) float  f32x4;
typedef __attribute__((ext_vector_type(8))) short  s16x8;
typedef __attribute__((ext_vector_type(8))) __bf16 bf16x8;
typedef __attribute__((ext_vector_type(2))) u32    u32x2;

#define DEV __device__ __forceinline__
#define SCALE_Q 0.1889822365046136f   // 28^-0.5

DEV float bf2f(u16 u){ u32 x = ((u32)u)<<16; float f; __builtin_memcpy(&f,&x,4); return f; }
DEV u16   f2bf(float f){ u32 x; __builtin_memcpy(&x,&f,4); return (u16)((x + 0x7fffu + ((x>>16)&1u))>>16); }

DEV s16x8 cvt8(const float* __restrict__ src){
  f32x4 f0 = *(const f32x4*)src, f1 = *(const f32x4*)(src+4);
  bf16x8 b;
  b[0]=(__bf16)f0[0]; b[1]=(__bf16)f0[1]; b[2]=(__bf16)f0[2]; b[3]=(__bf16)f0[3];
  b[4]=(__bf16)f1[0]; b[5]=(__bf16)f1[1]; b[6]=(__bf16)f1[2]; b[7]=(__bf16)f1[3];
  return __builtin_bit_cast(s16x8, b);
}

// async global->LDS, 16B per lane. LDS dest = wave-uniform base + lane*16.
DEV void gll16(const u16* g, u16* l){
  __builtin_amdgcn_global_load_lds(
      (const __attribute__((address_space(1))) u32*)(const void*)g,
      (__attribute__((address_space(3))) u32*)(void*)l,
      16, 0, 0);
}

DEV void ld28(const u16* __restrict__ p, float* dst, float scale){
#pragma unroll
  for (int j=0;j<7;j++){
    u32x2 w = *(const u32x2*)(p + j*4);
    dst[j*4+0] = bf2f((u16)(w[0]&0xffffu))*scale;
    dst[j*4+1] = bf2f((u16)(w[0]>>16))*scale;
    dst[j*4+2] = bf2f((u16)(w[1]&0xffffu))*scale;
    dst[j*4+3] = bf2f((u16)(w[1]>>16))*scale;
  }
}

// ---------------------------------------------------------------------------
// pack_k: f32 weights -> bf16 packed.
//  WqkvT [672][224], WoutT [448][224], convW [4][224][2016] ([conv][co][tap*224+ci], kd=1)
// ---------------------------------------------------------------------------
__global__ void pack_k(const float* __restrict__ Wq, const float* __restrict__ Wkv,
                       const float* __restrict__ Wout,
                       const float* __restrict__ wr, const float* __restrict__ w1,
                       const float* __restrict__ w2, const float* __restrict__ w3,
                       u16* __restrict__ WqkvT, u16* __restrict__ WoutT,
                       u16* __restrict__ convW)
{
  int idx = blockIdx.x*256 + threadIdx.x;
  if (idx < 150528) {
    int nn = idx/224, k = idx - nn*224;
    float v;
    if (nn < 224)      v = Wq [k*224 + nn];
    else if (nn < 448) v = Wkv[k*448 + (nn-224)];
    else               v = Wkv[k*448 + (nn-448) + 224];
    WqkvT[idx] = f2bf(v);
  } else if (idx < 250880) {
    int j = idx - 150528;
    int nn = j/224, k = j - nn*224;
    WoutT[j] = f2bf(Wout[k*448 + nn]);
  } else {
    int j = idx - 250880;
    int cv = j/451584, rem = j - cv*451584;
    int co = rem/2016, kk = rem - co*2016;
    int tap = kk/224, ci = kk - tap*224;
    const float* w = (cv==0)?wr:(cv==1)?w1:(cv==2)?w2:w3;
    convW[j] = f2bf(w[(co*224 + ci)*27 + 9 + tap]);
  }
}

// ---------------------------------------------------------------------------
// prep_k: x(f32,[65536][448]) -> x1bf (bf16 flat [65536][224])
//         and xpad (bf16 padded [64][34][34][224], zero borders);
//         also zero-borders oApad/oBpad.
// ---------------------------------------------------------------------------
__global__ void prep_k(const float* __restrict__ x, u16* __restrict__ x1bf,
                       u16* __restrict__ xpad, u16* __restrict__ oApad,
                       u16* __restrict__ oBpad)
{
  int idx = blockIdx.x*256 + threadIdx.x;   // 8092*256 = 2,071,552 = 73984*28
  int pp = idx/28, c8 = idx - pp*28;
  int b = pp/1156, rem = pp - b*1156, y = rem/34, xx = rem - y*34;
  int c0 = c8*8;
  if (y>=1 && y<=32 && xx>=1 && xx<=32){
    int p = (b*32 + y-1)*32 + (xx-1);
    *(s16x8*)(x1bf + p*224 + c0) = cvt8(x + p*448 + c0);
    *(s16x8*)(xpad + pp*224 + c0) = cvt8(x + p*448 + 224 + c0);
  } else {
    const s16x8 z = {0,0,0,0,0,0,0,0};
    *(s16x8*)(xpad  + pp*224 + c0) = z;
    *(s16x8*)(oApad + pp*224 + c0) = z;
    *(s16x8*)(oBpad + pp*224 + c0) = z;
  }
}

// ---------------------------------------------------------------------------
// GEMM: C[65536 x 224-per-nb] = A[65536 x K] * Bt^T (Bt [N][K] bf16).
// BM=128, BN=224, BK=32, 512 thr (8 waves 4Mx2N), wave tile 32x112 (2x7 frags).
// global_load_lds staging, double-buffered LDS (44 KB -> 2 blocks/CU),
// one barrier per K-step; inter-block TLP hides the vmcnt drain.
//
// LDS granule swizzle (bank-conflict fix, both-sides involution):
//   16B-granule g holds tile element (row = g>>2, q = ((g&3) - ((g>>4)&3))&3).
//   Stage: thread t writes granule t linearly; its SOURCE granule column is
//   qsrc = ((t&3) - ((t>>4)&3))&3.  Read (row r, col-granule lg) from
//   granule r*4 + ((lg + (r>>2))&3).  Quarter-wave lanes then spread 2-way
//   over all 8 granule-positions-mod-128B (2-way = free) instead of 8-way.
//
// Conv K-order is tap-INNER (tap=ks%9, kc=ks/9): 9 consecutive steps reuse
// the same activation rows (L2-hot) -> FETCH drops ~2.5x.
// XCD swizzle: bm = (x&7)*64 + x>>3 (grid.x=512) -> each XCD owns a
// contiguous pixel range; both nb panels share A in its L2.
// ---------------------------------------------------------------------------
enum { M_FUSED=0, M_C2=1, M_C3=2, M_QKV=3, M_OUT=4 };

template<int MODE>
__global__ __launch_bounds__(512,4) void gemm_k(
    const u16* __restrict__ A, const u16* __restrict__ Bt,
    const float* __restrict__ bias0, const float* __restrict__ bias1,
    u16* __restrict__ outA, u16* __restrict__ outB, float* __restrict__ outF)
{
  constexpr bool CONV = (MODE==M_FUSED || MODE==M_C2 || MODE==M_C3);
  constexpr int KTOT = CONV ? 2016 : 224;
  constexpr int KS   = KTOT/32;

  __shared__ __align__(16) u16 Als[2][128*32];   // 16 KB
  __shared__ __align__(16) u16 Bls[2][224*32];   // 28 KB

  const int t  = threadIdx.x;
  const int bmRaw = blockIdx.x, nb = blockIdx.y;
  const int bm = ((bmRaw&7)<<6) + (bmRaw>>3);    // XCD-contiguous (grid.x=512)
  const int lane = t&63, lr = lane&15, lg = lane>>4;
  const int w = t>>6, wm = w>>1, wn = w&1;

  // ---- staging source addresses (granule t; inverse-swizzled source col) ----
  const int arow = t>>2;
  const int qsrc = ((t&3) - ((t>>4)&3)) & 3;
  const int acol8 = qsrc*8;
  const int p0 = bm*128 + arow;
  int PP0 = 0;
  if constexpr (CONV) PP0 = ((p0>>10)*34 + ((p0>>5)&31) + 1)*34 + (p0&31) + 1;
  const int Bb0 = (nb*224 +       arow)*KTOT + acol8;   // granule t
  const int Bb1 = (nb*224 + 128 + arow)*KTOT + acol8;   // granule 512+t (t<384)

  // wave-uniform LDS dest bases (u16 units; granule c at byte c*16)
  u16* aBase[2] = { &Als[0][0] + w*512, &Als[1][0] + w*512 };
  u16* bBase[2] = { &Bls[0][0] + w*512, &Bls[1][0] + w*512 };

  auto STAGE = [&](int buf, int ks){
    if constexpr (CONV){
      const int kc  = ks/9;
      const int tap = ks - kc*9;          // tap-inner: rows stay L2-hot
      const int ty = tap/3, tx = tap - ty*3;
      const int toff = (ty-1)*34 + (tx-1);
      const int koff = tap*224 + kc*32;
      gll16(A + (PP0+toff)*224 + kc*32 + acol8, aBase[buf]);
      gll16(Bt + Bb0 + koff, bBase[buf]);
      if (w < 6) gll16(Bt + Bb1 + koff, bBase[buf] + 4096);
    } else {
      gll16(A + p0*224 + ks*32 + acol8, aBase[buf]);
      gll16(Bt + Bb0 + ks*32, bBase[buf]);
      if (w < 6) gll16(Bt + Bb1 + ks*32, bBase[buf] + 4096);
    }
  };

  f32x4 acc[2][7];
  { f32x4 zf = {0.f,0.f,0.f,0.f};
#pragma unroll
    for (int i=0;i<2;i++)
#pragma unroll
      for (int j=0;j<7;j++) acc[i][j] = zf; }

  STAGE(0, 0);
  __syncthreads();   // vmcnt(0) drained: buf0 ready

  for (int ks=0; ks<KS; ++ks){
    const int cur = ks&1;
    if (ks+1 < KS) STAGE(cur^1, ks+1);   // prefetch overlaps this iter's compute

    const u16* Ac = &Als[cur][0];
    const u16* Bc = &Bls[cur][0];
    bf16x8 af[2], bfv[7];
#pragma unroll
    for (int mi=0; mi<2; ++mi){
      const int row = wm*32 + mi*16 + lr;
      af[mi] = *(const bf16x8*)(Ac + row*32 + ((lg + (row>>2))&3)*8);
    }
#pragma unroll
    for (int ni=0; ni<7; ++ni){
      const int row = wn*112 + ni*16 + lr;
      bfv[ni] = *(const bf16x8*)(Bc + row*32 + ((lg + (row>>2))&3)*8);
    }

#pragma unroll
    for (int ni=0; ni<7; ++ni)
#pragma unroll
      for (int mi=0; mi<2; ++mi)
        acc[mi][ni] = __builtin_amdgcn_mfma_f32_16x16x32_bf16(af[mi], bfv[ni], acc[mi][ni], 0,0,0);

    __syncthreads();   // prefetch landed + all reads of cur done
  }

  // ---- epilogue ----
  const float* bs;
  if constexpr (MODE==M_FUSED) bs = (nb==0) ? bias0 : bias1;
  else bs = bias0;

#pragma unroll
  for (int mi=0; mi<2; ++mi){
    const int rbase = bm*128 + wm*32 + mi*16 + lg*4;
#pragma unroll
    for (int ni=0; ni<7; ++ni){
      const int col = wn*112 + ni*16 + lr;
#pragma unroll
      for (int r=0;r<4;r++){
        const int row = rbase + r;
        float v = acc[mi][ni][r];
        if constexpr (MODE==M_FUSED){
          v = fmaxf(v + bs[col], 0.f);
          if (nb==0){
            outF[row*672 + 448 + col] = v;         // res (f32, lives in d_out)
          } else {
            const int pp = ((row>>10)*34 + ((row>>5)&31) + 1)*34 + (row&31) + 1;
            outB[pp*224 + col] = f2bf(v);          // conv1 out (padded)
          }
        } else if constexpr (MODE==M_C2){
          v = fmaxf(v + bs[col], 0.f);
          const int pp = ((row>>10)*34 + ((row>>5)&31) + 1)*34 + (row&31) + 1;
          outB[pp*224 + col] = f2bf(v);            // conv2 out (padded)
        } else if constexpr (MODE==M_C3){
          v = fmaxf(v + bs[col], 0.f);
          const int o = row*672 + 448 + col;
          outF[o] = v + outF[o];                   // X2S = relu(conv3)+res
        } else if constexpr (MODE==M_QKV){
          outA[row*672 + nb*224 + col] = f2bf(v);  // qkv bf16 ws
        } else {                                   // M_OUT
          outF[row*672 + nb*224 + col] = v + bs[nb*224 + col];
        }
      }
    }
  }
}

// ---------------------------------------------------------------------------
// Branch-1 attention
// ---------------------------------------------------------------------------
__global__ __launch_bounds__(256,2) void attn1_k(const u16* __restrict__ qkv,
    const float* __restrict__ pos1, u16* __restrict__ attnout)
{
  __shared__ __align__(16) float KL[64][112];
  __shared__ __align__(16) float VL[64][112];
  const int t = threadIdx.x;
  const int b = blockIdx.x>>4, n = blockIdx.x&15;
  const int base = b*1024 + (n>>2)*256 + (n&3)*8;
  {
    const int r = t>>2, part = t&3;
    const int pr_ = base + (r>>3)*32 + (r&7);
    const u16* kp = qkv + pr_*672 + 224 + part*28;
    const u16* vp = kp + 224;
#pragma unroll
    for (int j=0;j<7;j++){
      u32x2 kk = *(const u32x2*)(kp + j*4);
      u32x2 vv = *(const u32x2*)(vp + j*4);
      const int c = part*28 + j*4;
      KL[r][c+0]=bf2f((u16)(kk[0]&0xffffu)); KL[r][c+1]=bf2f((u16)(kk[0]>>16));
      KL[r][c+2]=bf2f((u16)(kk[1]&0xffffu)); KL[r][c+3]=bf2f((u16)(kk[1]>>16));
      VL[r][c+0]=bf2f((u16)(vv[0]&0xffffu)); VL[r][c+1]=bf2f((u16)(vv[0]>>16));
      VL[r][c+2]=bf2f((u16)(vv[1]&0xffffu)); VL[r][c+3]=bf2f((u16)(vv[1]>>16));
    }
  }
  __syncthreads();

  const int h = t>>6, i = t&63;
  const int pi = base + (i>>3)*32 + (i&7);
  float q[28];
  ld28(qkv + pi*672 + h*28, q, SCALE_Q);

  float s[64];
  const float* pr = pos1 + (h*64+i)*64;
#pragma unroll
  for (int j4=0;j4<16;j4++){
    f32x4 pv = *(const f32x4*)(pr + j4*4);
    s[j4*4+0]=pv[0]; s[j4*4+1]=pv[1]; s[j4*4+2]=pv[2]; s[j4*4+3]=pv[3];
  }
  const int c0 = h*28;
#pragma unroll
  for (int j=0;j<64;j++){
    const f32x4* kr = (const f32x4*)&KL[j][c0];
    float a0=0.f,a1=0.f,a2=0.f,a3=0.f;
#pragma unroll
    for (int u=0;u<7;u++){
      f32x4 kv = kr[u];
      a0 += q[u*4+0]*kv[0]; a1 += q[u*4+1]*kv[1];
      a2 += q[u*4+2]*kv[2]; a3 += q[u*4+3]*kv[3];
    }
    s[j] += (a0+a1)+(a2+a3);
  }
  float mx = s[0];
#pragma unroll
  for (int j=1;j<64;j++) mx = fmaxf(mx, s[j]);
  float sum = 0.f;
#pragma unroll
  for (int j=0;j<64;j++){ float e = __expf(s[j]-mx); s[j]=e; sum+=e; }
  const float inv = 1.f/sum;

  float out[28];
#pragma unroll
  for (int u=0;u<28;u++) out[u]=0.f;
#pragma unroll
  for (int j=0;j<64;j++){
    const float pj = s[j];
    const f32x4* vr = (const f32x4*)&VL[j][c0];
#pragma unroll
    for (int u=0;u<7;u++){
      f32x4 vv = vr[u];
      out[u*4+0] += pj*vv[0]; out[u*4+1] += pj*vv[1];
      out[u*4+2] += pj*vv[2]; out[u*4+3] += pj*vv[3];
    }
  }
  u16* op = attnout + pi*224 + h*28;
#pragma unroll
  for (int u=0;u<7;u++){
    u32x2 wv;
    wv[0] = (u32)f2bf(out[u*4+0]*inv) | ((u32)f2bf(out[u*4+1]*inv)<<16);
    wv[1] = (u32)f2bf(out[u*4+2]*inv) | ((u32)f2bf(out[u*4+3]*inv)<<16);
    *(u32x2*)(op + u*4) = wv;
  }
}

// ---------------------------------------------------------------------------
// Branch-2 attention
// ---------------------------------------------------------------------------
__global__ __launch_bounds__(256,1) void attn2_k(const u16* __restrict__ qkv,
    const float* __restrict__ pos2, u16* __restrict__ attnout)
{
  const int t = threadIdx.x;
  const int b = blockIdx.x>>4, mg = blockIdx.x&15;
  const int m = mg*4 + (t>>6);
  const int lane = t&63, h = lane>>4, i = lane&15;
  const int base = b*1024 + (m>>3)*32 + (m&7);
  const int pi = base + (i>>2)*256 + (i&3)*8;

  float q[28];
  ld28(qkv + pi*672 + 112 + h*28, q, SCALE_Q);

  float s[16];
  const float* pr = pos2 + (h*16+i)*16;
#pragma unroll
  for (int j4=0;j4<4;j4++){
    f32x4 pv = *(const f32x4*)(pr + j4*4);
    s[j4*4+0]=pv[0]; s[j4*4+1]=pv[1]; s[j4*4+2]=pv[2]; s[j4*4+3]=pv[3];
  }
#pragma unroll
  for (int j=0;j<16;j++){
    const int pj_ = base + (j>>2)*256 + (j&3)*8;
    float kk[28];
    ld28(qkv + pj_*672 + 336 + h*28, kk, 1.0f);
    float a=0.f;
#pragma unroll
    for (int u=0;u<28;u++) a += q[u]*kk[u];
    s[j] += a;
  }
  float mx = s[0];
#pragma unroll
  for (int j=1;j<16;j++) mx = fmaxf(mx, s[j]);
  float sum = 0.f;
#pragma unroll
  for (int j=0;j<16;j++){ float e = __expf(s[j]-mx); s[j]=e; sum+=e; }
  const float inv = 1.f/sum;

  float out[28];
#pragma unroll
  for (int u=0;u<28;u++) out[u]=0.f;
#pragma unroll
  for (int j=0;j<16;j++){
    const int pj_ = base + (j>>2)*256 + (j&3)*8;
    float vv[28];
    ld28(qkv + pj_*672 + 560 + h*28, vv, 1.0f);
    const float pj = s[j];
#pragma unroll
    for (int u=0;u<28;u++) out[u] += pj*vv[u];
  }
  u16* op = attnout + pi*224 + 112 + h*28;
#pragma unroll
  for (int u=0;u<7;u++){
    u32x2 wv;
    wv[0] = (u32)f2bf(out[u*4+0]*inv) | ((u32)f2bf(out[u*4+1]*inv)<<16);
    wv[1] = (u32)f2bf(out[u*4+2]*inv) | ((u32)f2bf(out[u*4+3]*inv)<<16);
    *(u32x2*)(op + u*4) = wv;
  }
}

// ---------------------------------------------------------------------------
extern "C" void kernel_launch(void* const* d_in, const int* in_sizes, int n_in,
                              void* d_out, int out_size, void* d_ws, size_t ws_size,
                              hipStream_t stream) {
  const float* x    = (const float*)d_in[0];
  const float* pos1 = (const float*)d_in[1];
  const float* pos2 = (const float*)d_in[2];
  const float* Wq   = (const float*)d_in[3];
  const float* Wkv  = (const float*)d_in[4];
  const float* Wout = (const float*)d_in[5];
  const float* bout = (const float*)d_in[6];
  const float* wr   = (const float*)d_in[7];
  const float* br   = (const float*)d_in[8];
  const float* w1   = (const float*)d_in[9];
  const float* b1   = (const float*)d_in[10];
  const float* w2   = (const float*)d_in[11];
  const float* b2   = (const float*)d_in[12];
  const float* w3   = (const float*)d_in[13];
  const float* b3   = (const float*)d_in[14];

  char* ws = (char*)d_ws;
  const size_t PADSZ = 73984ull*224*2;          // 33,144,832
  const size_t FLATS = 65536ull*224*2;          // 29,360,128
  u16* xpad   = (u16*)(ws);                     // dead after fused conv
  u16* oApad  = (u16*)(ws + PADSZ);             // dead after conv2
  u16* oBpad  = (u16*)(ws + 2*PADSZ);           // dead after conv3
  u16* x1bf   = (u16*)(ws + 3*PADSZ);           // dead after qkv gemm
  u16* convW  = (u16*)(ws + 3*PADSZ + FLATS);
  u16* WqkvT  = convW + 4*451584;
  u16* WoutT  = WqkvT + 672*224;
  u16* qkv     = (u16*)(ws);                    // after convs done
  u16* attnout = (u16*)(ws + 88080384);
  float* dout  = (float*)d_out;

  pack_k<<<8036, 256, 0, stream>>>(Wq, Wkv, Wout, wr, w1, w2, w3, WqkvT, WoutT, convW);
  prep_k<<<8092, 256, 0, stream>>>(x, x1bf, xpad, oApad, oBpad);

  // conv chain: fused(convr->d_out ch448 f32 | conv1->oApad), conv2, conv3(+res)
  gemm_k<M_FUSED><<<dim3(512,2), 512, 0, stream>>>(xpad,  convW,          br, b1, nullptr, oApad, dout);
  gemm_k<M_C2  ><<<dim3(512,1), 512, 0, stream>>>(oApad, convW+2*451584, b2, nullptr, nullptr, oBpad, nullptr);
  gemm_k<M_C3  ><<<dim3(512,1), 512, 0, stream>>>(oBpad, convW+3*451584, b3, nullptr, nullptr, nullptr, dout);

  // attention: qkv gemm, two attn branches, out-proj
  gemm_k<M_QKV ><<<dim3(512,3), 512, 0, stream>>>(x1bf, WqkvT, nullptr, nullptr, qkv, nullptr, nullptr);
  attn1_k<<<1024, 256, 0, stream>>>(qkv, pos1, attnout);
  attn2_k<<<1024, 256, 0, stream>>>(qkv, pos2, attnout);
  gemm_k<M_OUT ><<<dim3(512,2), 512, 0, stream>>>(attnout, WoutT, bout, nullptr, nullptr, nullptr, dout);
}